// Round 12
// baseline (607.989 us; speedup 1.0000x reference)
//
#include <hip/hip_runtime.h>
#include <hip/hip_bf16.h>
#include <math.h>

#define HDIM   256
#define NHEAD  4
#define LLAY   4
#define TLAY   4
#define KMAXC  10
#define MAXD   32
#define BATCH  64
#define MSUB   32
#define KNODE  32
#define SSUB   2048
#define NNODE  65536
#define NEDGE  131072
#define EPSPER 64
#define EDN    5

typedef unsigned short u16;
typedef __attribute__((ext_vector_type(8))) short bf16x8;
typedef __attribute__((ext_vector_type(4))) float f32x4;

__device__ __forceinline__ float us2f(u16 u) {
    union { unsigned int i; float f; } x; x.i = ((unsigned int)u) << 16; return x.f;
}
__device__ __forceinline__ u16 f2us(float v) {
    union { float f; unsigned int i; } x; x.f = v;
    unsigned int u = x.i;
    u += 0x7fffu + ((u >> 16) & 1u);   // RNE
    return (u16)(u >> 16);
}
__device__ __forceinline__ float finite_or_zero(float v) {
    return (v == v && fabsf(v) <= 3.0e38f) ? v : 0.0f;
}
__device__ __forceinline__ void gll16(const u16* g, u16* l) {
    __builtin_amdgcn_global_load_lds(
        (const __attribute__((address_space(1))) unsigned int*)g,
        (__attribute__((address_space(3))) unsigned int*)l, 16, 0, 0);
}

// ---------------------------------------------------------------------------
// CSR precompute: per subgraph, edges sorted by local dst row.
__global__ __launch_bounds__(256) void k_csr(
    const int* __restrict__ src, const int* __restrict__ dst,
    const int* __restrict__ eid, u16* __restrict__ perm, u16* __restrict__ off)
{
    __shared__ int sL[4][64], dL[4][64], eL[4][64];
    int wave = threadIdx.x >> 6, lane = threadIdx.x & 63;
    int sgi = blockIdx.x * 4 + wave;
    sL[wave][lane] = src[sgi * 64 + lane] - sgi * KNODE;
    dL[wave][lane] = dst[sgi * 64 + lane] - sgi * KNODE;
    eL[wave][lane] = eid[sgi * 64 + lane];
    __syncthreads();
    if (lane < 32) {
        int cnt = 0;
        for (int e = 0; e < 64; ++e) cnt += (dL[wave][e] == lane) ? 1 : 0;
        int incl = cnt;
        #pragma unroll
        for (int d = 1; d < 32; d <<= 1) {
            int v = __shfl_up(incl, d, 64);
            if (lane >= d) incl += v;
        }
        int start = incl - cnt;
        off[sgi * 32 + lane] = (u16)start;
        int pos = start;
        for (int e = 0; e < 64; ++e) {
            if (dL[wave][e] == lane) {
                perm[sgi * 64 + pos] = (u16)((sL[wave][e] << 3) | eL[wave][e]);
                ++pos;
            }
        }
    }
}

// ---------------------------------------------------------------------------
// Weight transpose+convert: W (K x N f32, slice z) -> WT (N x K bf16).
__global__ __launch_bounds__(256) void k_wtrans(
    const float* __restrict__ W, u16* __restrict__ WT, int K, int N)
{
    __shared__ float til[32][33];
    int k0 = blockIdx.x * 32, n0 = blockIdx.y * 32, s = blockIdx.z;
    const float* Wb = W + (size_t)s * K * N;
    u16* Tb = WT + (size_t)s * N * K;
    int j = threadIdx.x & 31, i0 = threadIdx.x >> 5;
    #pragma unroll
    for (int it = 0; it < 4; ++it) {
        int i = i0 + it * 8;
        til[i][j] = Wb[(size_t)(k0 + i) * N + n0 + j];
    }
    __syncthreads();
    #pragma unroll
    for (int it = 0; it < 4; ++it) {
        int i = i0 + it * 8;
        Tb[(size_t)(n0 + i) * K + k0 + j] = f2us(til[j][i]);
    }
}

// ---------------------------------------------------------------------------
// Fully-fused GNN (verified R9/R11 body). launch_bounds(256,3): VGPR cap
// ~170 >= 88 used (no spill), 3 blocks/CU = 12 waves/CU for latency hiding.
__global__ __launch_bounds__(256, 3) void k_gnn4(
    const int* __restrict__ x_ids, const int* __restrict__ dist,
    const int* __restrict__ nodes, const float* __restrict__ lp,
    const float* __restrict__ atom_emb, const float* __restrict__ dist_emb,
    const float* __restrict__ logp_W, const float* __restrict__ logp_b,
    const u16* __restrict__ perm, const u16* __restrict__ off,
    const float* __restrict__ bond_emb, const float* __restrict__ eps_arr,
    const float* __restrict__ b1a, const float* __restrict__ b2a,
    const u16* __restrict__ W1T, const u16* __restrict__ W2T,
    float* __restrict__ x)
{
    __shared__ __align__(16) unsigned char smem[38912];
    u16*   hz    = (u16*)smem;
    float* bondL = (float*)(smem + 32768);
    u16*   permL = (u16*)(smem + 32768 + 5120);
    u16*   offL  = (u16*)(smem + 32768 + 5120 + 256);
    float* validL= (float*)(smem + 32768 + 5120 + 512);
    float* epsL  = (float*)(smem + 32768 + 5120 + 512 + 256);

    int tid = threadIdx.x, lane = tid & 63, wave = tid >> 6;
    int row0 = blockIdx.x * 64;
    int fr = lane & 15, quad = lane >> 4;

    for (int i = tid; i < EDN * 256; i += 256) bondL[i] = bond_emb[i];
    if (tid < 128) permL[tid] = perm[blockIdx.x * 128 + tid];
    if (tid < 64) {
        offL[tid] = off[blockIdx.x * 64 + tid];
        validL[tid] = (nodes[row0 + tid] >= 0) ? 1.0f : 0.0f;
    }
    if (tid < 4) epsL[tid] = eps_arr[tid];

    {
        int m = tid & 63, qd = tid >> 6;
        int rg = row0 + m;
        float valid = (nodes[rg] >= 0) ? 1.0f : 0.0f;
        float lpv = finite_or_zero(lp[rg >> 5]);
        int dc = dist[rg]; dc = dc < 0 ? 0 : (dc > MAXD ? MAXD : dc);
        int xid = x_ids[rg];
        #pragma unroll
        for (int k = 0; k < 8; ++k) {
            int cc = qd * 8 + k, c = cc * 8;
            float4 a0 = *reinterpret_cast<const float4*>(atom_emb + xid * 256 + c);
            float4 a1 = *reinterpret_cast<const float4*>(atom_emb + xid * 256 + c + 4);
            float4 d0 = *reinterpret_cast<const float4*>(dist_emb + dc * 256 + c);
            float4 d1 = *reinterpret_cast<const float4*>(dist_emb + dc * 256 + c + 4);
            float4 w0 = *reinterpret_cast<const float4*>(logp_W + c);
            float4 w1 = *reinterpret_cast<const float4*>(logp_W + c + 4);
            float4 p0 = *reinterpret_cast<const float4*>(logp_b + c);
            float4 p1 = *reinterpret_cast<const float4*>(logp_b + c + 4);
            union { bf16x8 v; ushort4 h[2]; } o;
            o.h[0] = (ushort4){
                f2us((a0.x + d0.x + fmaxf(lpv * w0.x + p0.x, 0.f)) * valid),
                f2us((a0.y + d0.y + fmaxf(lpv * w0.y + p0.y, 0.f)) * valid),
                f2us((a0.z + d0.z + fmaxf(lpv * w0.z + p0.z, 0.f)) * valid),
                f2us((a0.w + d0.w + fmaxf(lpv * w0.w + p0.w, 0.f)) * valid) };
            o.h[1] = (ushort4){
                f2us((a1.x + d1.x + fmaxf(lpv * w1.x + p1.x, 0.f)) * valid),
                f2us((a1.y + d1.y + fmaxf(lpv * w1.y + p1.y, 0.f)) * valid),
                f2us((a1.z + d1.z + fmaxf(lpv * w1.z + p1.z, 0.f)) * valid),
                f2us((a1.w + d1.w + fmaxf(lpv * w1.w + p1.w, 0.f)) * valid) };
            *reinterpret_cast<bf16x8*>(hz + m * 256 + ((cc ^ (m & 7)) * 8)) = o.v;
        }
    }
    __syncthreads();

    int rl = tid >> 3, g8 = tid & 7;
    for (int l = 0; l < LLAY; ++l) {
        float ep1 = 1.0f + epsL[l];
        for (int p = 0; p < 2; ++p) {
            int row = p * 32 + rl;
            int e0 = offL[p * 32 + rl];
            int e1 = (rl < 31) ? offL[p * 32 + rl + 1] : 64;
            float a[32];
            #pragma unroll
            for (int q = 0; q < 32; ++q) a[q] = 0.f;
            for (int j = e0; j < e1; ++j) {
                int ent = permL[p * 64 + j];
                int sl = p * 32 + (ent >> 3);
                int be = ent & 7;
                #pragma unroll
                for (int q = 0; q < 4; ++q) {
                    union { bf16x8 v; u16 s[8]; } hv;
                    hv.v = *reinterpret_cast<const bf16x8*>(
                        hz + sl * 256 + (((g8 * 4 + q) ^ (sl & 7)) * 8));
                    const float* bp = bondL + be * 256 + g8 * 32 + q * 8;
                    float4 bo0 = *reinterpret_cast<const float4*>(bp);
                    float4 bo1 = *reinterpret_cast<const float4*>(bp + 4);
                    a[q*8+0] += fmaxf(us2f(hv.s[0]) + bo0.x, 0.f);
                    a[q*8+1] += fmaxf(us2f(hv.s[1]) + bo0.y, 0.f);
                    a[q*8+2] += fmaxf(us2f(hv.s[2]) + bo0.z, 0.f);
                    a[q*8+3] += fmaxf(us2f(hv.s[3]) + bo0.w, 0.f);
                    a[q*8+4] += fmaxf(us2f(hv.s[4]) + bo1.x, 0.f);
                    a[q*8+5] += fmaxf(us2f(hv.s[5]) + bo1.y, 0.f);
                    a[q*8+6] += fmaxf(us2f(hv.s[6]) + bo1.z, 0.f);
                    a[q*8+7] += fmaxf(us2f(hv.s[7]) + bo1.w, 0.f);
                }
            }
            __syncthreads();
            #pragma unroll
            for (int q = 0; q < 4; ++q) {
                u16* ptr = hz + row * 256 + (((g8 * 4 + q) ^ (row & 7)) * 8);
                union { bf16x8 v; u16 s[8]; } hv, ov;
                hv.v = *reinterpret_cast<const bf16x8*>(ptr);
                #pragma unroll
                for (int k = 0; k < 8; ++k)
                    ov.s[k] = f2us(ep1 * us2f(hv.s[k]) + a[q * 8 + k]);
                *reinterpret_cast<bf16x8*>(ptr) = ov.v;
            }
        }
        __syncthreads();

        const u16* W1 = W1T + l * 65536;
        const float* b1 = b1a + l * 256;
        bf16x8 wf[4][8];
        #pragma unroll
        for (int i = 0; i < 4; ++i)
            #pragma unroll
            for (int kc = 0; kc < 8; ++kc)
                wf[i][kc] = *reinterpret_cast<const bf16x8*>(
                    W1 + (size_t)(wave * 64 + i * 16 + fr) * 256 + kc * 32 + quad * 8);
        f32x4 acc[4][4];
        #pragma unroll
        for (int i = 0; i < 4; ++i)
            #pragma unroll
            for (int j = 0; j < 4; ++j) acc[i][j] = (f32x4){0.f, 0.f, 0.f, 0.f};
        #pragma unroll
        for (int kc = 0; kc < 8; ++kc) {
            bf16x8 bfv[4];
            #pragma unroll
            for (int j = 0; j < 4; ++j) {
                int m = j * 16 + fr;
                bfv[j] = *reinterpret_cast<const bf16x8*>(hz + m * 256 + (((kc * 4 + quad) ^ (m & 7)) * 8));
            }
            #pragma unroll
            for (int i = 0; i < 4; ++i)
                #pragma unroll
                for (int j = 0; j < 4; ++j)
                    acc[i][j] = __builtin_amdgcn_mfma_f32_16x16x32_bf16(wf[i][kc], bfv[j], acc[i][j], 0, 0, 0);
        }
        __syncthreads();
        #pragma unroll
        for (int i = 0; i < 4; ++i) {
            int n1b = wave * 64 + i * 16 + quad * 4;
            float4 bb = *reinterpret_cast<const float4*>(b1 + n1b);
            #pragma unroll
            for (int j = 0; j < 4; ++j) {
                int m = j * 16 + fr;
                ushort4 o = { f2us(fmaxf(acc[i][j][0] + bb.x, 0.f)),
                              f2us(fmaxf(acc[i][j][1] + bb.y, 0.f)),
                              f2us(fmaxf(acc[i][j][2] + bb.z, 0.f)),
                              f2us(fmaxf(acc[i][j][3] + bb.w, 0.f)) };
                *reinterpret_cast<ushort4*>(hz + m * 256 + (((n1b >> 3) ^ (m & 7)) * 8) + (n1b & 7)) = o;
            }
        }
        __syncthreads();

        const u16* W2 = W2T + l * 65536;
        const float* b2 = b2a + l * 256;
        #pragma unroll
        for (int i = 0; i < 4; ++i)
            #pragma unroll
            for (int kc = 0; kc < 8; ++kc)
                wf[i][kc] = *reinterpret_cast<const bf16x8*>(
                    W2 + (size_t)(wave * 64 + i * 16 + fr) * 256 + kc * 32 + quad * 8);
        #pragma unroll
        for (int i = 0; i < 4; ++i)
            #pragma unroll
            for (int j = 0; j < 4; ++j) acc[i][j] = (f32x4){0.f, 0.f, 0.f, 0.f};
        #pragma unroll
        for (int kc = 0; kc < 8; ++kc) {
            bf16x8 bfv[4];
            #pragma unroll
            for (int j = 0; j < 4; ++j) {
                int m = j * 16 + fr;
                bfv[j] = *reinterpret_cast<const bf16x8*>(hz + m * 256 + (((kc * 4 + quad) ^ (m & 7)) * 8));
            }
            #pragma unroll
            for (int i = 0; i < 4; ++i)
                #pragma unroll
                for (int j = 0; j < 4; ++j)
                    acc[i][j] = __builtin_amdgcn_mfma_f32_16x16x32_bf16(wf[i][kc], bfv[j], acc[i][j], 0, 0, 0);
        }
        __syncthreads();

        if (l < LLAY - 1) {
            #pragma unroll
            for (int i = 0; i < 4; ++i) {
                int n2b = wave * 64 + i * 16 + quad * 4;
                float4 bb = *reinterpret_cast<const float4*>(b2 + n2b);
                #pragma unroll
                for (int j = 0; j < 4; ++j) {
                    int m = j * 16 + fr;
                    float vm = validL[m];
                    ushort4 o = { f2us((acc[i][j][0] + bb.x) * vm),
                                  f2us((acc[i][j][1] + bb.y) * vm),
                                  f2us((acc[i][j][2] + bb.z) * vm),
                                  f2us((acc[i][j][3] + bb.w) * vm) };
                    *reinterpret_cast<ushort4*>(hz + m * 256 + (((n2b >> 3) ^ (m & 7)) * 8) + (n2b & 7)) = o;
                }
            }
            __syncthreads();
        } else {
            if (fr == 0) {
                #pragma unroll
                for (int i = 0; i < 4; ++i) {
                    int n2b = wave * 64 + i * 16 + quad * 4;
                    float4 bb = *reinterpret_cast<const float4*>(b2 + n2b);
                    #pragma unroll
                    for (int jj = 0; jj < 2; ++jj) {
                        int j = jj * 2, m = j * 16;
                        float vm = validL[m];
                        float4 o = { (acc[i][j][0] + bb.x) * vm,
                                     (acc[i][j][1] + bb.y) * vm,
                                     (acc[i][j][2] + bb.z) * vm,
                                     (acc[i][j][3] + bb.w) * vm };
                        *reinterpret_cast<float4*>(
                            x + (size_t)(blockIdx.x * 2 + (m >> 5)) * 256 + n2b) = o;
                    }
                }
            }
        }
    }
}

// ---------------------------------------------------------------------------
// Overlap bias via 512-bit LDS bitmaps (verified R3 body).
__global__ __launch_bounds__(1024) void k_bias(
    const int* __restrict__ nodes, const float* __restrict__ lp,
    const float* __restrict__ ovl_emb, const float* __restrict__ alpha_p,
    float* __restrict__ bias)
{
    int b = blockIdx.x, tid = threadIdx.x;
    __shared__ int nd[32][32];
    __shared__ unsigned int bmv[32][17];
    __shared__ float lpc[32];
    __shared__ float emb[16];
    nd[tid >> 5][tid & 31] = nodes[b * 1024 + tid];
    if (tid < 512) bmv[tid >> 4][tid & 15] = 0u;
    if (tid < 32) {
        float l = finite_or_zero(lp[b * 32 + tid]);
        l = l < -30.f ? -30.f : (l > 0.f ? 0.f : l);
        lpc[tid] = l;
    }
    if (tid >= 64 && tid < 64 + KMAXC + 1) emb[tid - 64] = ovl_emb[tid - 64];
    __syncthreads();
    int own = nd[tid >> 5][tid & 31];
    if (own >= 0) atomicOr(&bmv[tid >> 5][own >> 5], 1u << (own & 31));
    __syncthreads();
    int i = tid >> 5, j = tid & 31;
    float alpha = alpha_p[0];
    int cnt = 0;
    #pragma unroll
    for (int k = 0; k < 32; ++k) {
        int nk = nd[i][k];
        if (nk >= 0) cnt += (int)((bmv[j][nk >> 5] >> (nk & 31)) & 1u);
    }
    bias[b * 1024 + tid] = emb[cnt > KMAXC ? KMAXC : cnt] - alpha * lpc[j];
}

// ---------------------------------------------------------------------------
// GEMM with fused LayerNorm on A: C = epi(LN(X) @ BT^T). X f32 [M][256].
// A resident in LDS (K=256, XOR-swizzled); B streamed via gll16 dbuf.
// 64x64 tile, 4 waves 2x2. act: 0 none, 2 gelu. Out bf16.
__global__ __launch_bounds__(256) void k_gemmA_ln(
    const float* __restrict__ X, const u16* __restrict__ BT,
    const float* __restrict__ ln_g, const float* __restrict__ ln_b,
    const float* __restrict__ bias, u16* __restrict__ C,
    int N, int act)
{
    __shared__ __align__(16) u16 As[64 * 256];     // 32 KB, swizzled
    __shared__ __align__(16) u16 Bs[2][64 * 32];   // 8 KB
    int tid = threadIdx.x, lane = tid & 63, wave = tid >> 6;
    int wm = wave >> 1, wn = wave & 1;
    int bm = blockIdx.y * 64, bn = blockIdx.x * 64;
    int fr = lane & 15, quad = lane >> 4;

    const u16* gB = BT + (size_t)(bn + wave * 16 + (lane >> 2)) * 256 + (lane & 3) * 8;
    gll16(gB, &Bs[0][wave * 512]);

    // LN: each wave 16 rows, write bf16 swizzled into As
    #pragma unroll
    for (int rr = 0; rr < 16; ++rr) {
        int r = wave * 16 + rr;
        float4 xv = *reinterpret_cast<const float4*>(X + (size_t)(bm + r) * 256 + lane * 4);
        float s = xv.x + xv.y + xv.z + xv.w;
        #pragma unroll
        for (int o2 = 32; o2 > 0; o2 >>= 1) s += __shfl_xor(s, o2);
        float mu = s * (1.0f / 256.0f);
        float d0 = xv.x - mu, d1 = xv.y - mu, d2 = xv.z - mu, d3 = xv.w - mu;
        float sq = d0 * d0 + d1 * d1 + d2 * d2 + d3 * d3;
        #pragma unroll
        for (int o2 = 32; o2 > 0; o2 >>= 1) sq += __shfl_xor(sq, o2);
        float rs = rsqrtf(sq * (1.0f / 256.0f) + 1e-5f);
        int c = lane * 4;
        float4 gv = *reinterpret_cast<const float4*>(ln_g + c);
        float4 bv = *reinterpret_cast<const float4*>(ln_b + c);
        ushort4 o = { f2us(d0 * rs * gv.x + bv.x), f2us(d1 * rs * gv.y + bv.y),
                      f2us(d2 * rs * gv.z + bv.z), f2us(d3 * rs * gv.w + bv.w) };
        *reinterpret_cast<ushort4*>(As + r * 256 + (((lane >> 1) ^ (r & 7)) * 8) + (lane & 1) * 4) = o;
    }
    __syncthreads();

    f32x4 acc[2][2];
    #pragma unroll
    for (int i = 0; i < 2; ++i)
        #pragma unroll
        for (int j = 0; j < 2; ++j) acc[i][j] = (f32x4){0.f, 0.f, 0.f, 0.f};
    for (int kc = 0; kc < 8; ++kc) {
        int buf = kc & 1;
        if (kc < 7) gll16(gB + (kc + 1) * 32, &Bs[buf ^ 1][wave * 512]);
        bf16x8 af[2], bfr[2];
        #pragma unroll
        for (int i = 0; i < 2; ++i) {
            int m = wm * 32 + i * 16 + fr;
            af[i] = *reinterpret_cast<const bf16x8*>(As + m * 256 + (((kc * 4 + quad) ^ (m & 7)) * 8));
        }
        #pragma unroll
        for (int j = 0; j < 2; ++j)
            bfr[j] = *reinterpret_cast<const bf16x8*>(&Bs[buf][(wn * 32 + j * 16 + fr) * 32 + quad * 8]);
        #pragma unroll
        for (int i = 0; i < 2; ++i)
            #pragma unroll
            for (int j = 0; j < 2; ++j)
                acc[i][j] = __builtin_amdgcn_mfma_f32_16x16x32_bf16(af[i], bfr[j], acc[i][j], 0, 0, 0);
        __syncthreads();
    }
    int crow0 = bm + wm * 32 + quad * 4;
    int ccol0 = bn + wn * 32 + fr;
    #pragma unroll
    for (int i = 0; i < 2; ++i) {
        #pragma unroll
        for (int r = 0; r < 4; ++r) {
            int m = crow0 + i * 16 + r;
            #pragma unroll
            for (int j = 0; j < 2; ++j) {
                int n = ccol0 + j * 16;
                float v = acc[i][j][r];
                if (bias) v += bias[n];
                if (act == 2) v = 0.5f * v * (1.0f + erff(v * 0.70710678118654752f));
                C[(size_t)m * N + n] = f2us(v);
            }
        }
    }
}

// ---------------------------------------------------------------------------
// 64x64-tile bf16 MFMA GEMM (verified R7/R8 body): A bf16, BT bf16, dbuf.
__global__ __launch_bounds__(256) void k_gemmB(
    const u16* __restrict__ A, const u16* __restrict__ BT,
    const float* __restrict__ bias, void* __restrict__ Cout, int c_is_bf16,
    const float* __restrict__ resid, const int* __restrict__ valid,
    int M, int K, int N, int act)
{
    __shared__ __align__(16) u16 As[2][64 * 32];
    __shared__ __align__(16) u16 Bs[2][64 * 32];
    int tid = threadIdx.x, lane = tid & 63, wave = tid >> 6;
    int wm = wave >> 1, wn = wave & 1;
    int bm = blockIdx.y * 64, bn = blockIdx.x * 64;
    const u16* gA = A + (size_t)(bm + wave * 16 + (lane >> 2)) * K + (lane & 3) * 8;
    const u16* gB = BT + (size_t)(bn + wave * 16 + (lane >> 2)) * K + (lane & 3) * 8;
    gll16(gA, &As[0][wave * 512]);
    gll16(gB, &Bs[0][wave * 512]);
    f32x4 acc[2][2];
    #pragma unroll
    for (int i = 0; i < 2; ++i)
        #pragma unroll
        for (int j = 0; j < 2; ++j) acc[i][j] = (f32x4){0.f, 0.f, 0.f, 0.f};
    int fr = lane & 15, quad = lane >> 4;
    int nit = K >> 5;
    __syncthreads();
    for (int it = 0; it < nit; ++it) {
        int buf = it & 1;
        if (it + 1 < nit) {
            int k0 = (it + 1) * 32;
            gll16(gA + k0, &As[buf ^ 1][wave * 512]);
            gll16(gB + k0, &Bs[buf ^ 1][wave * 512]);
        }
        bf16x8 af[2], bfr[2];
        #pragma unroll
        for (int i = 0; i < 2; ++i)
            af[i] = *reinterpret_cast<const bf16x8*>(&As[buf][(wm * 32 + i * 16 + fr) * 32 + quad * 8]);
        #pragma unroll
        for (int j = 0; j < 2; ++j)
            bfr[j] = *reinterpret_cast<const bf16x8*>(&Bs[buf][(wn * 32 + j * 16 + fr) * 32 + quad * 8]);
        #pragma unroll
        for (int i = 0; i < 2; ++i)
            #pragma unroll
            for (int j = 0; j < 2; ++j)
                acc[i][j] = __builtin_amdgcn_mfma_f32_16x16x32_bf16(af[i], bfr[j], acc[i][j], 0, 0, 0);
        __syncthreads();
    }
    int crow0 = bm + wm * 32 + quad * 4;
    int ccol0 = bn + wn * 32 + fr;
    #pragma unroll
    for (int i = 0; i < 2; ++i) {
        #pragma unroll
        for (int r = 0; r < 4; ++r) {
            int m = crow0 + i * 16 + r;
            float vm = valid ? ((valid[m] >= 0) ? 1.0f : 0.0f) : 1.0f;
            #pragma unroll
            for (int j = 0; j < 2; ++j) {
                int n = ccol0 + j * 16;
                float v = acc[i][j][r];
                if (bias) v += bias[n];
                if (act == 1) v = v > 0.f ? v : 0.f;
                else if (act == 2) v = 0.5f * v * (1.0f + erff(v * 0.70710678118654752f));
                v *= vm;
                if (resid) v += resid[(size_t)m * N + n];
                if (c_is_bf16) ((u16*)Cout)[(size_t)m * N + n] = f2us(v);
                else ((float*)Cout)[(size_t)m * N + n] = v;
            }
        }
    }
}

// ---------------------------------------------------------------------------
// Attention for one (batch b, head hh) — verified R8 body, qkv bf16 global.
__global__ __launch_bounds__(256) void k_attn(
    const u16* __restrict__ qkv, const float* __restrict__ bias, u16* __restrict__ o)
{
    int b = blockIdx.x >> 2, hh = blockIdx.x & 3;
    __shared__ float qs[32][65], ks[32][65], vs[32][65];
    __shared__ float sc[32][33];
    int tid = threadIdx.x;
    #pragma unroll
    for (int u = 0; u < 8; ++u) {
        int idx = tid + u * 256;
        int i = idx >> 6, d = idx & 63;
        size_t base = (size_t)(b * 32 + i) * 768;
        qs[i][d] = us2f(qkv[base + hh * 64 + d]);
        ks[i][d] = us2f(qkv[base + 256 + hh * 64 + d]);
        vs[i][d] = us2f(qkv[base + 512 + hh * 64 + d]);
    }
    __syncthreads();
    #pragma unroll
    for (int u = 0; u < 4; ++u) {
        int p = tid + u * 256;
        int i = p >> 5, j = p & 31;
        float s = 0.f;
        #pragma unroll
        for (int d = 0; d < 64; ++d) s += qs[i][d] * ks[j][d];
        sc[i][j] = s * 0.125f + bias[b * 1024 + i * 32 + j];
    }
    __syncthreads();
    if (tid < 32) {
        int i = tid;
        float m = -1e30f;
        for (int j = 0; j < 32; ++j) m = fmaxf(m, sc[i][j]);
        float sum = 0.f;
        for (int j = 0; j < 32; ++j) { float e = expf(sc[i][j] - m); sc[i][j] = e; sum += e; }
        float inv = 1.0f / sum;
        for (int j = 0; j < 32; ++j) sc[i][j] *= inv;
    }
    __syncthreads();
    #pragma unroll
    for (int u = 0; u < 8; ++u) {
        int idx = tid + u * 256;
        int i = idx >> 6, d = idx & 63;
        float a = 0.f;
        #pragma unroll
        for (int j = 0; j < 32; ++j) a += sc[i][j] * vs[j][d];
        o[(size_t)(b * 32 + i) * 256 + hh * 64 + d] = f2us(a);
    }
}

// ---------------------------------------------------------------------------
// Final LN + softmax(-lp_c)-weighted sum. Grid 64. (verified R11 body)
__global__ __launch_bounds__(256) void k_fin(
    const float* __restrict__ x, const float* __restrict__ lp,
    const float* __restrict__ lnout_g, const float* __restrict__ lnout_b,
    float* __restrict__ out)
{
    __shared__ __align__(16) float xlnf[32 * 260];
    __shared__ float wfin[32];
    int tid = threadIdx.x, lane = tid & 63, wave = tid >> 6;
    int b = blockIdx.x;
    #pragma unroll
    for (int rr = 0; rr < 8; ++rr) {
        int row = wave * 8 + rr;
        float4 xv = *reinterpret_cast<const float4*>(x + (size_t)(b * 32 + row) * 256 + lane * 4);
        float s = xv.x + xv.y + xv.z + xv.w;
        #pragma unroll
        for (int o2 = 32; o2 > 0; o2 >>= 1) s += __shfl_xor(s, o2);
        float mu = s * (1.0f / 256.0f);
        float d0 = xv.x - mu, d1 = xv.y - mu, d2 = xv.z - mu, d3 = xv.w - mu;
        float sq = d0 * d0 + d1 * d1 + d2 * d2 + d3 * d3;
        #pragma unroll
        for (int o2 = 32; o2 > 0; o2 >>= 1) sq += __shfl_xor(sq, o2);
        float rs = rsqrtf(sq * (1.0f / 256.0f) + 1e-5f);
        int c = lane * 4;
        float4 gv = *reinterpret_cast<const float4*>(lnout_g + c);
        float4 bv = *reinterpret_cast<const float4*>(lnout_b + c);
        float4 o = { d0 * rs * gv.x + bv.x, d1 * rs * gv.y + bv.y,
                     d2 * rs * gv.z + bv.z, d3 * rs * gv.w + bv.w };
        *reinterpret_cast<float4*>(xlnf + row * 260 + c) = o;
    }
    __syncthreads();
    if (tid == 0) {
        float l2[32];
        float m = -1e30f;
        for (int i = 0; i < 32; ++i) {
            float l = finite_or_zero(lp[b * 32 + i]);
            l = l < -30.f ? -30.f : (l > 0.f ? 0.f : l);
            l2[i] = -l;
            m = fmaxf(m, -l);
        }
        float s = 0.f;
        for (int i = 0; i < 32; ++i) { float e = expf(l2[i] - m); wfin[i] = e; s += e; }
        float inv = 1.0f / s;
        for (int i = 0; i < 32; ++i) wfin[i] *= inv;
    }
    __syncthreads();
    float a = 0.f;
    for (int i = 0; i < 32; ++i) a += wfin[i] * xlnf[i * 260 + tid];
    out[(size_t)b * 256 + tid] = a;
}

// ---------------------------------------------------------------------------
extern "C" void kernel_launch(void* const* d_in, const int* in_sizes, int n_in,
                              void* d_out, int out_size, void* d_ws, size_t ws_size,
                              hipStream_t stream)
{
    const int*   x_ids    = (const int*)d_in[0];
    const int*   edge_ids = (const int*)d_in[1];
    const int*   srcp     = (const int*)d_in[2];
    const int*   dstp     = (const int*)d_in[3];
    const int*   nodes    = (const int*)d_in[4];
    const int*   dist     = (const int*)d_in[5];
    const float* lp       = (const float*)d_in[6];
    const float* atom_emb = (const float*)d_in[7];
    const float* bond_emb = (const float*)d_in[8];
    const float* dist_emb = (const float*)d_in[9];
    const float* logp_W   = (const float*)d_in[10];
    const float* logp_b   = (const float*)d_in[11];
    const float* gnn_eps  = (const float*)d_in[12];
    const float* gnn_W1   = (const float*)d_in[13];
    const float* gnn_b1   = (const float*)d_in[14];
    const float* gnn_W2   = (const float*)d_in[15];
    const float* gnn_b2   = (const float*)d_in[16];
    const float* ln1_g    = (const float*)d_in[17];
    const float* ln1_b    = (const float*)d_in[18];
    const float* qkv_W    = (const float*)d_in[19];
    const float* out_W    = (const float*)d_in[20];
    const float* out_b    = (const float*)d_in[21];
    const float* ln2_g    = (const float*)d_in[22];
    const float* ln2_b    = (const float*)d_in[23];
    const float* f1_W     = (const float*)d_in[24];
    const float* f1_b     = (const float*)d_in[25];
    const float* f2_W     = (const float*)d_in[26];
    const float* f2_b     = (const float*)d_in[27];
    const float* lnout_g  = (const float*)d_in[28];
    const float* lnout_b  = (const float*)d_in[29];
    const float* ovl_emb  = (const float*)d_in[30];
    const float* alpha    = (const float*)d_in[31];

    char* ws = (char*)d_ws;
    u16*   gW1T  = (u16*)(ws + 100663296ull);
    u16*   gW2T  = (u16*)(ws + 100663296ull + 524288ull);
    u16*   permW = (u16*)(ws + 100663296ull + 1048576ull);
    u16*   offW  = (u16*)(ws + 100663296ull + 1310720ull);
    u16*   qkvT  = (u16*)(ws + 33554432ull);                 // 1.5 MB
    u16*   outT  = (u16*)(ws + 33554432ull + 1572864ull);    // 512 KB
    u16*   f1T   = (u16*)(ws + 33554432ull + 2097152ull);    // 2 MB
    u16*   f2T   = (u16*)(ws + 33554432ull + 4194304ull);    // 2 MB
    u16*   ob    = (u16*)(ws + 33554432ull + 6291456ull);    // 1 MB
    float* biasb = (float*)(ws + 33554432ull + 7340032ull);  // 256 KB
    u16*   qkvb  = (u16*)(ws + 33554432ull + 7602176ull);    // 3 MB
    u16*   ffh   = (u16*)(ws + 33554432ull + 10747904ull);   // 4 MB
    float* x     = (float*)(ws + 67108864ull);               // 2 MB f32

    k_csr<<<SSUB / 4, 256, 0, stream>>>(srcp, dstp, edge_ids, permW, offW);
    k_wtrans<<<dim3(8, 8, 4), 256, 0, stream>>>(gnn_W1, gW1T, 256, 256);
    k_wtrans<<<dim3(8, 8, 4), 256, 0, stream>>>(gnn_W2, gW2T, 256, 256);
    k_gnn4<<<NNODE / 64, 256, 0, stream>>>(
        x_ids, dist, nodes, lp, atom_emb, dist_emb, logp_W, logp_b,
        permW, offW, bond_emb, gnn_eps, gnn_b1, gnn_b2, gW1T, gW2T, x);
    k_wtrans<<<dim3(8, 24, 4), 256, 0, stream>>>(qkv_W, qkvT, 256, 768);
    k_wtrans<<<dim3(8, 8, 4), 256, 0, stream>>>(out_W, outT, 256, 256);
    k_wtrans<<<dim3(8, 32, 4), 256, 0, stream>>>(f1_W, f1T, 256, 1024);
    k_wtrans<<<dim3(32, 8, 4), 256, 0, stream>>>(f2_W, f2T, 1024, 256);
    k_bias<<<BATCH, 1024, 0, stream>>>(nodes, lp, ovl_emb, alpha, biasb);
    for (int t = 0; t < TLAY; ++t) {
        k_gemmA_ln<<<dim3(12, 32), 256, 0, stream>>>(
            x, qkvT + (size_t)t * 768 * 256, ln1_g + t * 256, ln1_b + t * 256,
            nullptr, qkvb, 768, 0);
        k_attn<<<BATCH * NHEAD, 256, 0, stream>>>(qkvb, biasb, ob);
        k_gemmB<<<dim3(4, 32), 256, 0, stream>>>(
            ob, outT + (size_t)t * 65536, out_b + t * 256, x, 0,
            x, nullptr, SSUB, 256, 256, 0);
        k_gemmA_ln<<<dim3(16, 32), 256, 0, stream>>>(
            x, f1T + (size_t)t * 1024 * 256, ln2_g + t * 256, ln2_b + t * 256,
            f1_b + t * 1024, ffh, 1024, 2);
        k_gemmB<<<dim3(4, 32), 256, 0, stream>>>(
            ffh, f2T + (size_t)t * 256 * 1024, f2_b + t * 256, x, 0,
            x, nullptr, SSUB, 1024, 256, 0);
    }
    k_fin<<<BATCH, 256, 0, stream>>>(x, lp, lnout_g, lnout_b, (float*)d_out);
}